// Round 1
// 417.861 us; speedup vs baseline: 1.0412x; 1.0412x over previous
//
#include <hip/hip_runtime.h>
#include <cstdint>
#include <cstddef>

#define N_NODES 8192
#define INF 512
#define OUTF 256
#define SPLITK 8
#define MSLICE (N_NODES / SPLITK)  // 1024
#define BN2 128                    // gemm2 n-tile (was 64)

typedef _Float16 f16;
typedef _Float16 f16x8 __attribute__((ext_vector_type(8)));
typedef _Float16 f16x4 __attribute__((ext_vector_type(4)));
typedef float f32x4 __attribute__((ext_vector_type(4)));

__device__ __forceinline__ void async_copy16(void* lds_dst, const void* g_src) {
  __builtin_amdgcn_global_load_lds(
      (const __attribute__((address_space(1))) void*)g_src,
      (__attribute__((address_space(3))) void*)lds_dst,
      16, 0, 0);
}

__device__ __forceinline__ float elu(float x) { return x > 0.f ? x : expm1f(x); }

// -------- prep: W [512][256] fp32 -> WhT [256][512] f16 (512 KB, tiny) -----
__global__ __launch_bounds__(256) void prep_w(const float* __restrict__ W,
                                              f16* __restrict__ WhT) {
  const int idx = blockIdx.x * 256 + threadIdx.x;  // 131072
  const int o = idx >> 9, i = idx & 511;
  WhT[idx] = (f16)W[i * OUTF + o];  // write coalesced; read via L2 (512 KB)
}

// -------- gemm1: supT[o][m] = sum_k WhT[o][k] * X[m][k]  (X cast fused) ----
// Tile 64o x 64m, BK=64, 8 iters. Grid (4,128)=512 blocks => 2/CU.
__global__ __launch_bounds__(256) void gemm1(const f16* __restrict__ WhT,
                                             const float* __restrict__ X,
                                             f16* __restrict__ supT) {
  __shared__ __align__(16) f16 Asm[64 * 64];  // WhT tile, XOR chunk-swizzled
  __shared__ __align__(16) f16 Bsm[64 * 64];  // X tile (f16), XOR-swizzled
  const int t = threadIdx.x;
  const int wave = t >> 6, lane = t & 63;
  const int q = lane >> 4, r = lane & 15;
  const int lrow = lane >> 3, lchunk = lane & 7;
  const int o0 = blockIdx.x * 64, m0 = blockIdx.y * 64;

  f32x4 acc[4];
#pragma unroll
  for (int i = 0; i < 4; ++i) acc[i] = (f32x4){0.f, 0.f, 0.f, 0.f};

  const int b_row = t >> 2;       // m' 0..63
  const int b_c0 = (t & 3) * 2;   // first of 2 logical chunks
  const float* xptr = X + (size_t)(m0 + b_row) * INF + (t & 3) * 16;

  for (int kt = 0; kt < 8; ++kt) {
    const int k0 = kt * 64;
    // A: async DMA, swizzle on source chunk (dst must be base + lane*16)
#pragma unroll
    for (int op = 0; op < 2; ++op) {
      const int row = (wave * 2 + op) * 8 + lrow;
      const f16* src = WhT + (size_t)(o0 + row) * INF + k0 + (lchunk ^ lrow) * 8;
      async_copy16(Asm + (wave * 2 + op) * 512, src);
    }
    // B: 16 fp32 per thread, cvt f16, 2x ds_write_b128 XOR-swizzled
    {
      const float* xp = xptr + k0;
      f32x4 v0 = *(const f32x4*)(xp + 0);
      f32x4 v1 = *(const f32x4*)(xp + 4);
      f32x4 v2 = *(const f32x4*)(xp + 8);
      f32x4 v3 = *(const f32x4*)(xp + 12);
      f16x8 h0, h1;
#pragma unroll
      for (int u = 0; u < 4; ++u) {
        h0[u] = (f16)v0[u];
        h0[4 + u] = (f16)v1[u];
        h1[u] = (f16)v2[u];
        h1[4 + u] = (f16)v3[u];
      }
      *(f16x8*)&Bsm[b_row * 64 + ((b_c0 ^ (b_row & 7)) * 8)] = h0;
      *(f16x8*)&Bsm[b_row * 64 + (((b_c0 + 1) ^ (b_row & 7)) * 8)] = h1;
    }
    __syncthreads();
#pragma unroll
    for (int s = 0; s < 2; ++s) {
      const int pc = ((s * 4 + q) ^ (r & 7)) * 8;
      f16x8 af[4];
#pragma unroll
      for (int i = 0; i < 4; ++i) af[i] = *(const f16x8*)&Asm[(i * 16 + r) * 64 + pc];
      const f16x8 bf = *(const f16x8*)&Bsm[(wave * 16 + r) * 64 + pc];
#pragma unroll
      for (int i = 0; i < 4; ++i)
        acc[i] = __builtin_amdgcn_mfma_f32_16x16x32_f16(af[i], bf, acc[i], 0, 0, 0);
    }
    __syncthreads();
  }
  // C/D: row(o)=q*4+g, col(m)=r
  const int m = m0 + wave * 16 + r;
#pragma unroll
  for (int i = 0; i < 4; ++i)
#pragma unroll
    for (int g = 0; g < 4; ++g)
      supT[(size_t)(o0 + i * 16 + q * 4 + g) * N_NODES + m] = (f16)acc[i][g];
}

// -------- gemm2: P16[y][n][o] = sum_{m in slice y} adj[n][m]^2 * supT[o][m] --
// 128n x 256o tile, BK=64, split-K=8. 512 threads (8 waves as 2n x 4o).
// LDS = 48 KB => 2 blocks/CU = 16 waves/CU. Grid 512 (1-D): y = wg&7 pins
// each split-K slice to one XCD (round-robin dispatch) so its 512 KB supT
// slice stays L2-resident against the adj stream.
template <bool ATOMIC>
__global__ __launch_bounds__(512, 4) void gemm2(const float* __restrict__ adj,
                                                const f16* __restrict__ supT,
                                                f16* __restrict__ P16,
                                                float* __restrict__ outp) {
  __shared__ __align__(16) f16 Asm[BN2 * 64];  // adj^2 tile, XOR-swizzled (16 KB)
  __shared__ __align__(16) f16 Bsm[256 * 64];  // supT tile, XOR-swizzled (32 KB)
  const int t = threadIdx.x;
  const int wave = t >> 6, lane = t & 63;
  const int q = lane >> 4, r = lane & 15;
  const int wn = wave >> 2, wo = wave & 3;  // wave tile: 64n x 64o
  const int wg = blockIdx.x;
  const int y = wg & 7;          // split-K slice == XCD id under round-robin
  const int n0 = (wg >> 3) * BN2;
  const size_t m_base = (size_t)y * MSLICE;

  f32x4 acc[4][4];
#pragma unroll
  for (int i = 0; i < 4; ++i)
#pragma unroll
    for (int j = 0; j < 4; ++j) acc[i][j] = (f32x4){0.f, 0.f, 0.f, 0.f};

  const int a_row = t >> 2;        // 0..127
  const int a_c0 = (t & 3) * 2;
  const float* aptr = adj + (size_t)(n0 + a_row) * N_NODES + m_base + (t & 3) * 16;
  const int b_o8 = lane >> 3;      // row within an 8-row copy group
  const int b_kb = lane & 7;

  for (int kt = 0; kt < MSLICE / 64; ++kt) {
    // B: async DMA, 4 copies per wave (32 total), swizzle on SOURCE chunk
#pragma unroll
    for (int j = 0; j < 4; ++j) {
      const int c = wave * 4 + j;          // 0..31 -> rows c*8..c*8+7
      const int o = c * 8 + b_o8;
      const int kb = b_kb ^ (o & 7);
      const f16* src = supT + (size_t)o * N_NODES + m_base + kt * 64 + kb * 8;
      async_copy16(Bsm + c * 8 * 64, src);
    }
    // A: 16 fp32, square, cvt, 2x ds_write_b128 XOR-swizzled
    {
      const float* ap = aptr + kt * 64;
      f32x4 v0 = *(const f32x4*)(ap + 0);
      f32x4 v1 = *(const f32x4*)(ap + 4);
      f32x4 v2 = *(const f32x4*)(ap + 8);
      f32x4 v3 = *(const f32x4*)(ap + 12);
      f16x8 h0, h1;
#pragma unroll
      for (int u = 0; u < 4; ++u) {
        h0[u] = (f16)(v0[u] * v0[u]);
        h0[4 + u] = (f16)(v1[u] * v1[u]);
        h1[u] = (f16)(v2[u] * v2[u]);
        h1[4 + u] = (f16)(v3[u] * v3[u]);
      }
      *(f16x8*)&Asm[a_row * 64 + ((a_c0 ^ (a_row & 7)) * 8)] = h0;
      *(f16x8*)&Asm[a_row * 64 + (((a_c0 + 1) ^ (a_row & 7)) * 8)] = h1;
    }
    __syncthreads();
#pragma unroll
    for (int s = 0; s < 2; ++s) {
      const int pc = ((s * 4 + q) ^ (r & 7)) * 8;
      f16x8 af[4], bf[4];
#pragma unroll
      for (int i = 0; i < 4; ++i)
        af[i] = *(const f16x8*)&Asm[(wn * 64 + i * 16 + r) * 64 + pc];
#pragma unroll
      for (int j = 0; j < 4; ++j)
        bf[j] = *(const f16x8*)&Bsm[(wo * 64 + j * 16 + r) * 64 + pc];
#pragma unroll
      for (int i = 0; i < 4; ++i)
#pragma unroll
        for (int j = 0; j < 4; ++j)
          acc[i][j] = __builtin_amdgcn_mfma_f32_16x16x32_f16(af[i], bf[j],
                                                             acc[i][j], 0, 0, 0);
    }
    __syncthreads();
  }
  if (ATOMIC) {
#pragma unroll
    for (int i = 0; i < 4; ++i)
#pragma unroll
      for (int g = 0; g < 4; ++g) {
        const int n = n0 + wn * 64 + i * 16 + q * 4 + g;
        float* orow = outp + (size_t)n * OUTF + wo * 64 + r;
#pragma unroll
        for (int j = 0; j < 4; ++j) atomicAdd(orow + j * 16, acc[i][j][g]);
      }
  } else {
    f16* base = P16 + (size_t)y * N_NODES * OUTF;
#pragma unroll
    for (int i = 0; i < 4; ++i)
#pragma unroll
      for (int g = 0; g < 4; ++g) {
        const int n = n0 + wn * 64 + i * 16 + q * 4 + g;
        f16* orow = base + (size_t)n * OUTF + wo * 64 + r;
#pragma unroll
        for (int j = 0; j < 4; ++j) orow[j * 16] = (f16)acc[i][j][g];
      }
  }
}

// -------- epilogue A: sum 8 f16 partial planes + bias + ELU (16B loads) ----
__global__ __launch_bounds__(256) void reduce_elu(const f16* __restrict__ P16,
                                                  const float* __restrict__ bias,
                                                  float* __restrict__ out) {
  const int idx = blockIdx.x * 256 + threadIdx.x;  // f16x8 index, 262144 total
  float s[8];
#pragma unroll
  for (int u = 0; u < 8; ++u) s[u] = 0.f;
#pragma unroll
  for (int y = 0; y < SPLITK; ++y) {
    const f16x8 h = ((const f16x8*)(P16 + (size_t)y * N_NODES * OUTF))[idx];
#pragma unroll
    for (int u = 0; u < 8; ++u) s[u] += (float)h[u];
  }
  const float* bp = bias + (idx & 31) * 8;
  f32x4 v0, v1;
#pragma unroll
  for (int u = 0; u < 4; ++u) {
    v0[u] = elu(s[u] + bp[u]);
    v1[u] = elu(s[4 + u] + bp[4 + u]);
  }
  ((f32x4*)out)[idx * 2 + 0] = v0;
  ((f32x4*)out)[idx * 2 + 1] = v1;
}

// -------- epilogue B (atomic fallback): in-place bias + ELU --------
__global__ __launch_bounds__(256) void bias_elu(float* __restrict__ out,
                                                const float* __restrict__ bias) {
  const int idx = blockIdx.x * 256 + threadIdx.x;
  f32x4 v = ((const f32x4*)out)[idx];
  const f32x4 b = ((const f32x4*)bias)[idx & 63];
#pragma unroll
  for (int u = 0; u < 4; ++u) v[u] = elu(v[u] + b[u]);
  ((f32x4*)out)[idx] = v;
}

extern "C" void kernel_launch(void* const* d_in, const int* in_sizes, int n_in,
                              void* d_out, int out_size, void* d_ws, size_t ws_size,
                              hipStream_t stream) {
  const float* X = (const float*)d_in[0];     // [8192, 512]
  const float* adj = (const float*)d_in[1];   // [8192, 8192]
  const float* W = (const float*)d_in[2];     // [512, 256]
  const float* bias = (const float*)d_in[3];  // [256]
  float* out = (float*)d_out;                 // [8192, 256] fp32

  char* ws = (char*)d_ws;
  f16* supT = (f16*)(ws + 0);           // 4 MB
  f16* WhT = (f16*)(ws + (4u << 20));   // 256 KB
  f16* P16 = (f16*)(ws + (8u << 20));   // 32 MB f16 partials
  const size_t need = (40u << 20);

  prep_w<<<INF * OUTF / 256, 256, 0, stream>>>(W, WhT);
  gemm1<<<dim3(OUTF / 64, N_NODES / 64), 256, 0, stream>>>(WhT, X, supT);
  if (ws_size >= need) {
    gemm2<false><<<dim3((N_NODES / BN2) * SPLITK), dim3(512), 0, stream>>>(adj, supT, P16, nullptr);
    reduce_elu<<<N_NODES * OUTF / 8 / 256, 256, 0, stream>>>(P16, bias, out);
  } else {
    hipMemsetAsync(d_out, 0, (size_t)out_size * sizeof(float), stream);
    gemm2<true><<<dim3((N_NODES / BN2) * SPLITK), dim3(512), 0, stream>>>(adj, supT, nullptr, out);
    bias_elu<<<N_NODES * OUTF / 4 / 256, 256, 0, stream>>>(out, bias);
  }
}